// Round 3
// baseline (549.206 us; speedup 1.0000x reference)
//
#include <hip/hip_runtime.h>
#include <math.h>

// ---------------------------------------------------------------------------
// Fully fused QFNN forward: ONE block per image, zero workspace usage.
// All intermediates in LDS with plain NCHW indexing. Correctness-first.
// ---------------------------------------------------------------------------
__global__ __launch_bounds__(256) void k_fused(
    const float* __restrict__ x,
    const float* __restrict__ c1w, const float* __restrict__ c1b,
    const float* __restrict__ c2w, const float* __restrict__ c2b,
    const float* __restrict__ fc1w, const float* __restrict__ fc1b,
    const float* __restrict__ fc2w, const float* __restrict__ fc2b,
    const float* __restrict__ fc3w, const float* __restrict__ fc3b,
    const float* __restrict__ qw,
    const float* __restrict__ fc4w, const float* __restrict__ fc4b,
    float* __restrict__ out)
{
    __shared__ float img[30*30];      // padded 28x28 input
    __shared__ float p1[32*16*17];    // pooled1, padded: [ic][row 0..15][col 0..16]
    __shared__ float p2[3136];        // pooled2 flat NCHW: oc*49 + py*7 + px
    __shared__ float h1s[128];
    __shared__ float h2s[64];
    __shared__ float fts[16];

    const int b = blockIdx.x, t = threadIdx.x;

    for (int i = t; i < 900;  i += 256) img[i] = 0.f;
    for (int i = t; i < 8704; i += 256) p1[i]  = 0.f;
    __syncthreads();
    const float* xi = x + (size_t)b * 784;
    for (int i = t; i < 784; i += 256)
        img[(i/28 + 1)*30 + (i%28 + 1)] = xi[i];
    __syncthreads();

    // ---- conv1 (1->32, 3x3 SAME) + ReLU + maxpool2 -> p1 interior ----
    for (int i = t; i < 6272; i += 256) {            // 32 oc * 196 pos
        const int oc = i / 196, pos = i % 196;
        const int py = pos / 14, px = pos % 14;
        const float bv = c1b[oc];
        float mx = 0.f;                               // relu(max) == max(0, max)
        #pragma unroll
        for (int dy = 0; dy < 2; ++dy)
        #pragma unroll
        for (int dx = 0; dx < 2; ++dx) {
            const int yy = 2*py + dy, xx = 2*px + dx; // conv-out coords 0..27
            float acc = bv;
            #pragma unroll
            for (int ky = 0; ky < 3; ++ky)
            #pragma unroll
            for (int kx = 0; kx < 3; ++kx)
                acc = fmaf(img[(yy+ky)*30 + xx+kx], c1w[oc*9 + ky*3 + kx], acc);
            mx = fmaxf(mx, acc);
        }
        p1[oc*272 + (py+1)*17 + (px+1)] = mx;
    }
    __syncthreads();

    // ---- conv2 (32->64, 3x3 SAME) + ReLU + maxpool2 -> p2 ----
    for (int i = t; i < 3136; i += 256) {            // 64 oc * 49 pos
        const int oc = i / 49, p = i % 49;
        const int py = p / 7, px = p % 7;
        const float bv = c2b[oc];
        float a00 = bv, a01 = bv, a10 = bv, a11 = bv;
        for (int ic = 0; ic < 32; ++ic) {
            const float* pp = p1 + ic*272;
            const float* wk = c2w + (oc*32 + ic)*9;
            #pragma unroll
            for (int ky = 0; ky < 3; ++ky)
            #pragma unroll
            for (int kx = 0; kx < 3; ++kx) {
                const float w = wk[ky*3 + kx];
                const int r0 = (2*py + ky)*17 + 2*px + kx;  // dy=0,dx=0
                a00 = fmaf(pp[r0],      w, a00);
                a01 = fmaf(pp[r0 + 1],  w, a01);
                a10 = fmaf(pp[r0 + 17], w, a10);
                a11 = fmaf(pp[r0 + 18], w, a11);
            }
        }
        const float mx = fmaxf(fmaxf(a00, a01), fmaxf(a10, a11));
        p2[i] = fmaxf(mx, 0.f);                      // i == oc*49 + py*7 + px
    }
    __syncthreads();

    // ---- fc1 (3136 -> 128) + ReLU ----
    if (t < 128) {
        float a = fc1b[t];
        const float* wr = fc1w + (size_t)t * 3136;
        for (int k = 0; k < 3136; ++k) a = fmaf(p2[k], wr[k], a);
        h1s[t] = fmaxf(a, 0.f);
    }
    __syncthreads();

    // ---- fc2 (128 -> 64) + ReLU ----
    if (t < 64) {
        float a = fc2b[t];
        const float* wr = fc2w + t * 128;
        for (int k = 0; k < 128; ++k) a = fmaf(h1s[k], wr[k], a);
        h2s[t] = fmaxf(a, 0.f);
    }
    __syncthreads();

    // ---- fc3 (64 -> 16) + ReLU ----
    if (t < 16) {
        float a = fc3b[t];
        const float* wr = fc3w + t * 64;
        for (int k = 0; k < 64; ++k) a = fmaf(h2s[k], wr[k], a);
        fts[t] = fmaxf(a, 0.f);
    }
    __syncthreads();

    // ---- quantum circuit + fc4 + log_softmax: serial on thread 0 ----
    if (t == 0) {
        float feat[16];
        #pragma unroll
        for (int j = 0; j < 16; ++j) feat[j] = fts[j];

        float nrm2 = 0.f;
        #pragma unroll
        for (int j = 0; j < 16; ++j) nrm2 += feat[j]*feat[j];
        const float inv = 1.f / fmaxf(sqrtf(nrm2), 1e-12f);
        float ar[16], ai[16];
        #pragma unroll
        for (int j = 0; j < 16; ++j) { ar[j] = feat[j]*inv; ai[j] = 0.f; }

        #pragma unroll
        for (int layer = 0; layer < 2; ++layer) {
            #pragma unroll
            for (int q = 0; q < 4; ++q) {
                const float phi = qw[(layer*4 + q)*3 + 0];
                const float th  = qw[(layer*4 + q)*3 + 1];
                const float om  = qw[(layer*4 + q)*3 + 2];
                float st, ct; sincosf(0.5f*th, &st, &ct);
                float sa, ca; sincosf(0.5f*(phi + om), &sa, &ca); // ep = ca - i sa
                float sb, cb; sincosf(0.5f*(phi - om), &sb, &cb); // em = cb + i sb
                // U = [[ep*c, -em*s], [conj(em)*s, conj(ep)*c]]
                const float U00r =  ca*ct, U00i = -sa*ct;
                const float U01r = -cb*st, U01i = -sb*st;
                const float U10r =  cb*st, U10i = -sb*st;
                const float U11r =  ca*ct, U11i =  sa*ct;
                const int stride = 1 << (3 - q);       // qubit q <-> bit (3-q)
                #pragma unroll
                for (int i0 = 0; i0 < 16; ++i0) {
                    if (i0 & stride) continue;
                    const int i1 = i0 | stride;
                    const float r0 = ar[i0], m0 = ai[i0];
                    const float r1 = ar[i1], m1 = ai[i1];
                    ar[i0] = U00r*r0 - U00i*m0 + U01r*r1 - U01i*m1;
                    ai[i0] = U00r*m0 + U00i*r0 + U01r*m1 + U01i*r1;
                    ar[i1] = U10r*r0 - U10i*m0 + U11r*r1 - U11i*m1;
                    ai[i1] = U10r*m0 + U10i*r0 + U11r*m1 + U11i*r1;
                }
            }
            #pragma unroll
            for (int q = 0; q < 3; ++q) {   // CNOT control=q, target=q+1
                const int cbit = 1 << (3 - q), tbit = 1 << (2 - q);
                #pragma unroll
                for (int idx = 0; idx < 16; ++idx) {
                    if ((idx & cbit) && !(idx & tbit)) {
                        const int j = idx | tbit;
                        float tr = ar[idx]; ar[idx] = ar[j]; ar[j] = tr;
                        float ti = ai[idx]; ai[idx] = ai[j]; ai[j] = ti;
                    }
                }
            }
        }

        float qo[4];
        #pragma unroll
        for (int q = 0; q < 4; ++q) {
            const int pb = 1 << (3 - q);
            float s = 0.f;
            #pragma unroll
            for (int idx = 0; idx < 16; ++idx) {
                const float pv = ar[idx]*ar[idx] + ai[idx]*ai[idx];
                s += (idx & pb) ? -pv : pv;
            }
            qo[q] = s;                       // <Z_q> = P(bit=0) - P(bit=1)
        }

        float z[10];
        float mx = -1e30f;
        #pragma unroll
        for (int o = 0; o < 10; ++o) {
            float a = fc4b[o];
            #pragma unroll
            for (int j = 0; j < 16; ++j) a = fmaf(feat[j], fc4w[o*20 + j], a);
            #pragma unroll
            for (int j = 0; j < 4;  ++j) a = fmaf(qo[j],  fc4w[o*20 + 16 + j], a);
            z[o] = a; mx = fmaxf(mx, a);
        }
        float se = 0.f;
        #pragma unroll
        for (int o = 0; o < 10; ++o) se += expf(z[o] - mx);
        const float lse = logf(se);
        #pragma unroll
        for (int o = 0; o < 10; ++o) out[(size_t)b*10 + o] = z[o] - mx - lse;
    }
}

// ---------------------------------------------------------------------------
extern "C" void kernel_launch(void* const* d_in, const int* in_sizes, int n_in,
                              void* d_out, int out_size, void* d_ws, size_t ws_size,
                              hipStream_t stream) {
    const float* x     = (const float*)d_in[0];
    const float* c1w   = (const float*)d_in[1];
    const float* c1b   = (const float*)d_in[2];
    const float* c2w   = (const float*)d_in[3];
    const float* c2b   = (const float*)d_in[4];
    const float* fc1w  = (const float*)d_in[5];
    const float* fc1b  = (const float*)d_in[6];
    const float* fc2w  = (const float*)d_in[7];
    const float* fc2b  = (const float*)d_in[8];
    const float* fc3w  = (const float*)d_in[9];
    const float* fc3b  = (const float*)d_in[10];
    const float* qwp   = (const float*)d_in[11];
    const float* fc4w  = (const float*)d_in[12];
    const float* fc4b  = (const float*)d_in[13];
    float* outp = (float*)d_out;

    k_fused<<<1024, 256, 0, stream>>>(x, c1w, c1b, c2w, c2b, fc1w, fc1b,
                                      fc2w, fc2b, fc3w, fc3b, qwp, fc4w, fc4b,
                                      outp);
}

// Round 4
// 281.389 us; speedup vs baseline: 1.9518x; 1.9518x over previous
//
#include <hip/hip_runtime.h>
#include <math.h>

// ---------------------------------------------------------------------------
// Fully fused QFNN forward: ONE block per image. Round 4: bank-conflict-free
// conv structure + register-blocked conv2 + split-k vectorized fc1.
// ---------------------------------------------------------------------------
__global__ __launch_bounds__(256) void k_fused(
    const float* __restrict__ x,
    const float* __restrict__ c1w, const float* __restrict__ c1b,
    const float* __restrict__ c2w, const float* __restrict__ c2b,
    const float* __restrict__ fc1w, const float* __restrict__ fc1b,
    const float* __restrict__ fc2w, const float* __restrict__ fc2b,
    const float* __restrict__ fc3w, const float* __restrict__ fc3b,
    const float* __restrict__ qw,
    const float* __restrict__ fc4w, const float* __restrict__ fc4b,
    float* __restrict__ out)
{
    // img: padded 30x30, columns SWIZZLED: stored col = (c>>1) + (c&1)*15
    __shared__ __align__(16) float img[900];
    __shared__ __align__(16) float p1[32*272];    // [32 ic][16 row][17 col] padded
    __shared__ __align__(16) float ctmp[32*197];  // conv2 raw out, [ocl][y*14+x]
    __shared__ __align__(16) float p2[3136];      // NCHW flat: oc*49 + py*7 + px
    __shared__ __align__(16) float h1p[2][128];
    __shared__ __align__(16) float h1s[128];
    __shared__ __align__(16) float h2s[64];
    __shared__ __align__(16) float fts[16];

    const int b = blockIdx.x, t = threadIdx.x;
    const int lane = t & 63, wv = t >> 6;

    for (int i = t; i < 900;  i += 256) img[i] = 0.f;
    for (int i = t; i < 8704; i += 256) p1[i]  = 0.f;
    __syncthreads();
    const float* xi = x + (size_t)b * 784;
    for (int i = t; i < 784; i += 256) {
        const int r = i / 28, c = i % 28;
        const int cp = c + 1;                       // padded col 1..28
        const int cs = (cp >> 1) + (cp & 1) * 15;   // swizzle
        img[(r + 1)*30 + cs] = xi[i];
    }
    __syncthreads();

    // ---- conv1 (1->32) + ReLU + maxpool2 -> p1 interior (round-3 logic,
    //      swizzled img reads: stride-1 across lanes per (dy,dx,ky,kx)) ----
    for (int i = t; i < 6272; i += 256) {            // 32 oc * 196 pos
        const int oc = i / 196, pos = i % 196;
        const int py = pos / 14, px = pos % 14;
        const float bv = c1b[oc];
        float mx = 0.f;                               // relu(max) == max(0,max)
        #pragma unroll
        for (int dy = 0; dy < 2; ++dy)
        #pragma unroll
        for (int dx = 0; dx < 2; ++dx) {
            const int yy = 2*py + dy, xx = 2*px + dx;
            float acc = bv;
            #pragma unroll
            for (int ky = 0; ky < 3; ++ky)
            #pragma unroll
            for (int kx = 0; kx < 3; ++kx) {
                const int cc = xx + kx;               // 0..29 (unswizzled)
                const int cs = (cc >> 1) + (cc & 1) * 15;
                acc = fmaf(img[(yy+ky)*30 + cs], c1w[oc*9 + ky*3 + kx], acc);
            }
            mx = fmaxf(mx, acc);
        }
        p1[oc*272 + (py+1)*17 + (px+1)] = mx;
    }
    __syncthreads();

    // ---- conv2 (32->64) + ReLU + maxpool2, register-blocked ----
    // Lanes <-> 196 conv positions (stride-1 LDS reads). Wave <-> 8 oc.
    // Two passes of 32 oc through ctmp, pooled into p2.
    for (int g = 0; g < 2; ++g) {
        const int ocb = __builtin_amdgcn_readfirstlane(g*32 + wv*8);
        int badr[4];
        #pragma unroll
        for (int ch = 0; ch < 4; ++ch) {
            int pos = ch*64 + lane; if (pos > 195) pos = 195;
            badr[ch] = (pos/14)*17 + (pos%14);
        }
        float acc[4][8];
        #pragma unroll
        for (int o = 0; o < 8; ++o) {
            const float bv = c2b[ocb + o];
            #pragma unroll
            for (int ch = 0; ch < 4; ++ch) acc[ch][o] = bv;
        }
        for (int ic = 0; ic < 32; ++ic) {
            // wave-uniform weights: 8 oc x 9
            float wk[8][9];
            const float* wb = c2w + (size_t)ocb*288 + ic*9;
            #pragma unroll
            for (int o = 0; o < 8; ++o)
                #pragma unroll
                for (int k = 0; k < 9; ++k) wk[o][k] = wb[o*288 + k];
            const float* pp = p1 + ic*272;
            #pragma unroll
            for (int ch = 0; ch < 4; ++ch) {
                float v[9];
                #pragma unroll
                for (int ky = 0; ky < 3; ++ky)
                #pragma unroll
                for (int kx = 0; kx < 3; ++kx)
                    v[ky*3+kx] = pp[badr[ch] + ky*17 + kx];
                #pragma unroll
                for (int o = 0; o < 8; ++o)
                    #pragma unroll
                    for (int k = 0; k < 9; ++k)
                        acc[ch][o] = fmaf(v[k], wk[o][k], acc[ch][o]);
            }
        }
        #pragma unroll
        for (int ch = 0; ch < 4; ++ch) {
            const int pos = ch*64 + lane;
            if (pos < 196) {
                #pragma unroll
                for (int o = 0; o < 8; ++o)
                    ctmp[(wv*8 + o)*197 + pos] = acc[ch][o];
            }
        }
        __syncthreads();
        for (int i2 = t; i2 < 1568; i2 += 256) {       // 32 oc * 49 pooled
            const int oc = i2 / 49, p = i2 % 49;
            const int py = p / 7, px = p % 7;
            const float* cc = ctmp + oc*197 + (2*py)*14 + 2*px;
            const float mx = fmaxf(fmaxf(cc[0], cc[1]), fmaxf(cc[14], cc[15]));
            p2[g*1568 + i2] = fmaxf(mx, 0.f);
        }
        __syncthreads();
    }

    // ---- fc1 (3136 -> 128) + ReLU: 2 threads per output row, float4 ----
    {
        const int o = t & 127, half = t >> 7;
        const float* wr = fc1w + (size_t)o*3136 + half*1568;
        const float* pp = p2 + half*1568;
        float a = 0.f;
        for (int k = 0; k < 1568; k += 4) {
            const float4 w4 = *(const float4*)(wr + k);
            const float4 p4 = *(const float4*)(pp + k);
            a = fmaf(w4.x, p4.x, a); a = fmaf(w4.y, p4.y, a);
            a = fmaf(w4.z, p4.z, a); a = fmaf(w4.w, p4.w, a);
        }
        h1p[half][o] = a;
    }
    __syncthreads();
    if (t < 128) h1s[t] = fmaxf(h1p[0][t] + h1p[1][t] + fc1b[t], 0.f);
    __syncthreads();

    // ---- fc2 (128 -> 64) + ReLU ----
    if (t < 64) {
        float a = fc2b[t];
        const float* wr = fc2w + t * 128;
        for (int k = 0; k < 128; ++k) a = fmaf(h1s[k], wr[k], a);
        h2s[t] = fmaxf(a, 0.f);
    }
    __syncthreads();

    // ---- fc3 (64 -> 16) + ReLU ----
    if (t < 16) {
        float a = fc3b[t];
        const float* wr = fc3w + t * 64;
        for (int k = 0; k < 64; ++k) a = fmaf(h2s[k], wr[k], a);
        fts[t] = fmaxf(a, 0.f);
    }
    __syncthreads();

    // ---- quantum circuit + fc4 + log_softmax: serial on thread 0 ----
    if (t == 0) {
        float feat[16];
        #pragma unroll
        for (int j = 0; j < 16; ++j) feat[j] = fts[j];

        float nrm2 = 0.f;
        #pragma unroll
        for (int j = 0; j < 16; ++j) nrm2 += feat[j]*feat[j];
        const float inv = 1.f / fmaxf(sqrtf(nrm2), 1e-12f);
        float ar[16], ai[16];
        #pragma unroll
        for (int j = 0; j < 16; ++j) { ar[j] = feat[j]*inv; ai[j] = 0.f; }

        #pragma unroll
        for (int layer = 0; layer < 2; ++layer) {
            #pragma unroll
            for (int q = 0; q < 4; ++q) {
                const float phi = qw[(layer*4 + q)*3 + 0];
                const float th  = qw[(layer*4 + q)*3 + 1];
                const float om  = qw[(layer*4 + q)*3 + 2];
                float st, ct; sincosf(0.5f*th, &st, &ct);
                float sa, ca; sincosf(0.5f*(phi + om), &sa, &ca); // ep = ca - i sa
                float sb, cb; sincosf(0.5f*(phi - om), &sb, &cb); // em = cb + i sb
                const float U00r =  ca*ct, U00i = -sa*ct;
                const float U01r = -cb*st, U01i = -sb*st;
                const float U10r =  cb*st, U10i = -sb*st;
                const float U11r =  ca*ct, U11i =  sa*ct;
                const int stride = 1 << (3 - q);
                #pragma unroll
                for (int i0 = 0; i0 < 16; ++i0) {
                    if (i0 & stride) continue;
                    const int i1 = i0 | stride;
                    const float r0 = ar[i0], m0 = ai[i0];
                    const float r1 = ar[i1], m1 = ai[i1];
                    ar[i0] = U00r*r0 - U00i*m0 + U01r*r1 - U01i*m1;
                    ai[i0] = U00r*m0 + U00i*r0 + U01r*m1 + U01i*r1;
                    ar[i1] = U10r*r0 - U10i*m0 + U11r*r1 - U11i*m1;
                    ai[i1] = U10r*m0 + U10i*r0 + U11r*m1 + U11i*r1;
                }
            }
            #pragma unroll
            for (int q = 0; q < 3; ++q) {   // CNOT control=q, target=q+1
                const int cbit = 1 << (3 - q), tbit = 1 << (2 - q);
                #pragma unroll
                for (int idx = 0; idx < 16; ++idx) {
                    if ((idx & cbit) && !(idx & tbit)) {
                        const int j = idx | tbit;
                        float tr = ar[idx]; ar[idx] = ar[j]; ar[j] = tr;
                        float ti = ai[idx]; ai[idx] = ai[j]; ai[j] = ti;
                    }
                }
            }
        }

        float qo[4];
        #pragma unroll
        for (int q = 0; q < 4; ++q) {
            const int pb = 1 << (3 - q);
            float s = 0.f;
            #pragma unroll
            for (int idx = 0; idx < 16; ++idx) {
                const float pv = ar[idx]*ar[idx] + ai[idx]*ai[idx];
                s += (idx & pb) ? -pv : pv;
            }
            qo[q] = s;
        }

        float z[10];
        float mx = -1e30f;
        #pragma unroll
        for (int o = 0; o < 10; ++o) {
            float a = fc4b[o];
            #pragma unroll
            for (int j = 0; j < 16; ++j) a = fmaf(feat[j], fc4w[o*20 + j], a);
            #pragma unroll
            for (int j = 0; j < 4;  ++j) a = fmaf(qo[j],  fc4w[o*20 + 16 + j], a);
            z[o] = a; mx = fmaxf(mx, a);
        }
        float se = 0.f;
        #pragma unroll
        for (int o = 0; o < 10; ++o) se += expf(z[o] - mx);
        const float lse = logf(se);
        #pragma unroll
        for (int o = 0; o < 10; ++o) out[(size_t)b*10 + o] = z[o] - mx - lse;
    }
}

// ---------------------------------------------------------------------------
extern "C" void kernel_launch(void* const* d_in, const int* in_sizes, int n_in,
                              void* d_out, int out_size, void* d_ws, size_t ws_size,
                              hipStream_t stream) {
    const float* x     = (const float*)d_in[0];
    const float* c1w   = (const float*)d_in[1];
    const float* c1b   = (const float*)d_in[2];
    const float* c2w   = (const float*)d_in[3];
    const float* c2b   = (const float*)d_in[4];
    const float* fc1w  = (const float*)d_in[5];
    const float* fc1b  = (const float*)d_in[6];
    const float* fc2w  = (const float*)d_in[7];
    const float* fc2b  = (const float*)d_in[8];
    const float* fc3w  = (const float*)d_in[9];
    const float* fc3b  = (const float*)d_in[10];
    const float* qwp   = (const float*)d_in[11];
    const float* fc4w  = (const float*)d_in[12];
    const float* fc4b  = (const float*)d_in[13];
    float* outp = (float*)d_out;

    k_fused<<<1024, 256, 0, stream>>>(x, c1w, c1b, c2w, c2b, fc1w, fc1b,
                                      fc2w, fc2b, fc3w, fc3b, qwp, fc4w, fc4b,
                                      outp);
}

// Round 6
// 178.686 us; speedup vs baseline: 3.0736x; 1.5748x over previous
//
#include <hip/hip_runtime.h>
#include <math.h>

// ---------------------------------------------------------------------------
// Fully fused QFNN forward, ONE block (256 thr) per image. Round 6:
// = round 5 with conv1's lane->position mapping FIXED (196 pooled positions,
// not 49). Convs use b64 LDS reads + register reuse across 8 oc per wave.
// ---------------------------------------------------------------------------
__global__ __launch_bounds__(256) void k_fused(
    const float* __restrict__ x,
    const float* __restrict__ c1w, const float* __restrict__ c1b,
    const float* __restrict__ c2w, const float* __restrict__ c2b,
    const float* __restrict__ fc1w, const float* __restrict__ fc1b,
    const float* __restrict__ fc2w, const float* __restrict__ fc2b,
    const float* __restrict__ fc3w, const float* __restrict__ fc3b,
    const float* __restrict__ qw,
    const float* __restrict__ fc4w, const float* __restrict__ fc4b,
    float* __restrict__ out)
{
    __shared__ __align__(16) float p1[32*288];   // [ic][16 rows][18 cols], zero border
    __shared__ __align__(16) float p2[3136];     // union: img(900) during conv1, then p2 NCHW
    __shared__ float h1s[128];
    __shared__ float h2s[64];
    __shared__ float fts[16];

    const int b = blockIdx.x, t = threadIdx.x;
    const int lane = t & 63, wv = t >> 6;
    const int p  = lane < 49 ? lane : 48;        // conv2 pooled position (7x7)
    const int py = p / 7, px = p % 7;

    // init
    for (int i = t; i < 9216; i += 256) p1[i] = 0.f;
    float* img = p2;                              // 30x30 padded, stride 30
    for (int i = t; i < 900; i += 256) img[i] = 0.f;
    __syncthreads();
    const float* xi = x + (size_t)b * 784;
    for (int i = t; i < 784; i += 256)
        img[(i/28 + 1)*30 + (i%28 + 1)] = xi[i];
    __syncthreads();

    // ---- conv1 (1->32) + ReLU + maxpool2 -> p1 ----
    // wave -> 8 oc; lane covers 4 of the 196 pooled positions (14x14).
    {
        const int ocb1 = __builtin_amdgcn_readfirstlane(wv*8);
        float wk[8][9], bv[8];
        #pragma unroll
        for (int o = 0; o < 8; ++o) {
            bv[o] = c1b[ocb1 + o];
            #pragma unroll
            for (int k = 0; k < 9; ++k) wk[o][k] = c1w[(ocb1 + o)*9 + k];
        }
        #pragma unroll
        for (int ch = 0; ch < 4; ++ch) {
            int pos = ch*64 + lane;
            const bool act = pos < 196;
            if (!act) pos = 195;
            const int qy = pos / 14, qx = pos % 14;
            const float* ib = img + (2*qy)*30 + 2*qx;
            float v[4][4];
            #pragma unroll
            for (int rr = 0; rr < 4; ++rr) {
                const float2 a = *(const float2*)(ib + rr*30);
                const float2 c = *(const float2*)(ib + rr*30 + 2);
                v[rr][0]=a.x; v[rr][1]=a.y; v[rr][2]=c.x; v[rr][3]=c.y;
            }
            #pragma unroll
            for (int o = 0; o < 8; ++o) {
                float m = 0.f;                    // relu(max) == max(0, max)
                #pragma unroll
                for (int dy = 0; dy < 2; ++dy)
                #pragma unroll
                for (int dx = 0; dx < 2; ++dx) {
                    float acc = bv[o];
                    #pragma unroll
                    for (int ky = 0; ky < 3; ++ky)
                    #pragma unroll
                    for (int kx = 0; kx < 3; ++kx)
                        acc = fmaf(v[dy+ky][dx+kx], wk[o][ky*3+kx], acc);
                    m = fmaxf(m, acc);
                }
                if (act) p1[(ocb1 + o)*288 + (qy+1)*18 + (qx+1)] = m;
            }
        }
    }
    __syncthreads();                              // img dead after this point

    // ---- conv2 (32->64) + ReLU + maxpool2 -> p2 ----
    // wave -> 8 oc per pass (2 passes), lane -> pooled pos (49 of 64 active).
    // Per ic: 8 ds_read_b64 (16 vals) feed 288 FMA (8 oc x 2x2 x 9).
    for (int g = 0; g < 2; ++g) {
        const int ocb = __builtin_amdgcn_readfirstlane(g*32 + wv*8);
        float acc[8][2][2];
        #pragma unroll
        for (int o = 0; o < 8; ++o) {
            const float bvv = c2b[ocb + o];
            acc[o][0][0]=bvv; acc[o][0][1]=bvv; acc[o][1][0]=bvv; acc[o][1][1]=bvv;
        }
        for (int ic = 0; ic < 32; ++ic) {
            const float* pp = p1 + ic*288 + (2*py)*18 + 2*px;
            float v[4][4];
            #pragma unroll
            for (int rr = 0; rr < 4; ++rr) {
                const float2 a = *(const float2*)(pp + rr*18);
                const float2 c = *(const float2*)(pp + rr*18 + 2);
                v[rr][0]=a.x; v[rr][1]=a.y; v[rr][2]=c.x; v[rr][3]=c.y;
            }
            const float* wb = c2w + (size_t)ocb*288 + ic*9;
            #pragma unroll
            for (int o = 0; o < 8; ++o) {
                float wk2[9];
                #pragma unroll
                for (int k = 0; k < 9; ++k) wk2[k] = wb[o*288 + k];
                #pragma unroll
                for (int dy = 0; dy < 2; ++dy)
                #pragma unroll
                for (int dx = 0; dx < 2; ++dx)
                    #pragma unroll
                    for (int ky = 0; ky < 3; ++ky)
                    #pragma unroll
                    for (int kx = 0; kx < 3; ++kx)
                        acc[o][dy][dx] = fmaf(v[dy+ky][dx+kx], wk2[ky*3+kx],
                                              acc[o][dy][dx]);
            }
        }
        if (lane < 49) {
            #pragma unroll
            for (int o = 0; o < 8; ++o) {
                const float mx = fmaxf(fmaxf(acc[o][0][0], acc[o][0][1]),
                                       fmaxf(acc[o][1][0], acc[o][1][1]));
                p2[(ocb + o)*49 + p] = fmaxf(mx, 0.f);
            }
        }
    }
    __syncthreads();

    // ---- fc1 (3136 -> 128) + ReLU ----
    // wave -> 32 rows (8 passes x 4 rows), lane -> k-slice; coalesced weights,
    // one LDS b128 shared by 4 rows; shfl_xor reduction.
    for (int pass = 0; pass < 8; ++pass) {
        const int o = wv*32 + pass*4;
        const float* w0 = fc1w + (size_t)o*3136;
        float a0=0.f, a1=0.f, a2=0.f, a3=0.f;
        for (int kb = 0; kb < 3072; kb += 256) {
            const int k = kb + lane*4;
            const float4 pv = *(const float4*)&p2[k];
            const float4 q0 = *(const float4*)(w0 + k);
            const float4 q1 = *(const float4*)(w0 + 3136 + k);
            const float4 q2 = *(const float4*)(w0 + 6272 + k);
            const float4 q3 = *(const float4*)(w0 + 9408 + k);
            a0 = fmaf(pv.x,q0.x,fmaf(pv.y,q0.y,fmaf(pv.z,q0.z,fmaf(pv.w,q0.w,a0))));
            a1 = fmaf(pv.x,q1.x,fmaf(pv.y,q1.y,fmaf(pv.z,q1.z,fmaf(pv.w,q1.w,a1))));
            a2 = fmaf(pv.x,q2.x,fmaf(pv.y,q2.y,fmaf(pv.z,q2.z,fmaf(pv.w,q2.w,a2))));
            a3 = fmaf(pv.x,q3.x,fmaf(pv.y,q3.y,fmaf(pv.z,q3.z,fmaf(pv.w,q3.w,a3))));
        }
        if (lane < 16) {                           // tail 3072..3135
            const int k = 3072 + lane*4;
            const float4 pv = *(const float4*)&p2[k];
            const float4 q0 = *(const float4*)(w0 + k);
            const float4 q1 = *(const float4*)(w0 + 3136 + k);
            const float4 q2 = *(const float4*)(w0 + 6272 + k);
            const float4 q3 = *(const float4*)(w0 + 9408 + k);
            a0 = fmaf(pv.x,q0.x,fmaf(pv.y,q0.y,fmaf(pv.z,q0.z,fmaf(pv.w,q0.w,a0))));
            a1 = fmaf(pv.x,q1.x,fmaf(pv.y,q1.y,fmaf(pv.z,q1.z,fmaf(pv.w,q1.w,a1))));
            a2 = fmaf(pv.x,q2.x,fmaf(pv.y,q2.y,fmaf(pv.z,q2.z,fmaf(pv.w,q2.w,a2))));
            a3 = fmaf(pv.x,q3.x,fmaf(pv.y,q3.y,fmaf(pv.z,q3.z,fmaf(pv.w,q3.w,a3))));
        }
        #pragma unroll
        for (int s = 1; s < 64; s <<= 1) {
            a0 += __shfl_xor(a0, s);
            a1 += __shfl_xor(a1, s);
            a2 += __shfl_xor(a2, s);
            a3 += __shfl_xor(a3, s);
        }
        if (lane == ((o+0)&63)) h1s[o+0] = fmaxf(a0 + fc1b[o+0], 0.f);
        if (lane == ((o+1)&63)) h1s[o+1] = fmaxf(a1 + fc1b[o+1], 0.f);
        if (lane == ((o+2)&63)) h1s[o+2] = fmaxf(a2 + fc1b[o+2], 0.f);
        if (lane == ((o+3)&63)) h1s[o+3] = fmaxf(a3 + fc1b[o+3], 0.f);
    }
    __syncthreads();

    // ---- fc2 (128 -> 64) + ReLU ----
    if (t < 64) {
        float a = fc2b[t];
        const float* wr = fc2w + t * 128;
        for (int k = 0; k < 128; ++k) a = fmaf(h1s[k], wr[k], a);
        h2s[t] = fmaxf(a, 0.f);
    }
    __syncthreads();

    // ---- fc3 (64 -> 16) + ReLU ----
    if (t < 16) {
        float a = fc3b[t];
        const float* wr = fc3w + t * 64;
        for (int k = 0; k < 64; ++k) a = fmaf(h2s[k], wr[k], a);
        fts[t] = fmaxf(a, 0.f);
    }
    __syncthreads();

    // ---- quantum circuit + fc4 + log_softmax: serial on thread 0 (verified) ----
    if (t == 0) {
        float feat[16];
        #pragma unroll
        for (int j = 0; j < 16; ++j) feat[j] = fts[j];

        float nrm2 = 0.f;
        #pragma unroll
        for (int j = 0; j < 16; ++j) nrm2 += feat[j]*feat[j];
        const float inv = 1.f / fmaxf(sqrtf(nrm2), 1e-12f);
        float ar[16], ai[16];
        #pragma unroll
        for (int j = 0; j < 16; ++j) { ar[j] = feat[j]*inv; ai[j] = 0.f; }

        #pragma unroll
        for (int layer = 0; layer < 2; ++layer) {
            #pragma unroll
            for (int q = 0; q < 4; ++q) {
                const float phi = qw[(layer*4 + q)*3 + 0];
                const float th  = qw[(layer*4 + q)*3 + 1];
                const float om  = qw[(layer*4 + q)*3 + 2];
                float st, ct; sincosf(0.5f*th, &st, &ct);
                float sa, ca; sincosf(0.5f*(phi + om), &sa, &ca); // ep = ca - i sa
                float sb, cb; sincosf(0.5f*(phi - om), &sb, &cb); // em = cb + i sb
                const float U00r =  ca*ct, U00i = -sa*ct;
                const float U01r = -cb*st, U01i = -sb*st;
                const float U10r =  cb*st, U10i = -sb*st;
                const float U11r =  ca*ct, U11i =  sa*ct;
                const int stride = 1 << (3 - q);
                #pragma unroll
                for (int i0 = 0; i0 < 16; ++i0) {
                    if (i0 & stride) continue;
                    const int i1 = i0 | stride;
                    const float r0 = ar[i0], m0 = ai[i0];
                    const float r1 = ar[i1], m1 = ai[i1];
                    ar[i0] = U00r*r0 - U00i*m0 + U01r*r1 - U01i*m1;
                    ai[i0] = U00r*m0 + U00i*r0 + U01r*m1 + U01i*r1;
                    ar[i1] = U10r*r0 - U10i*m0 + U11r*r1 - U11i*m1;
                    ai[i1] = U10r*m0 + U10i*r0 + U11r*m1 + U11i*r1;
                }
            }
            #pragma unroll
            for (int q = 0; q < 3; ++q) {   // CNOT control=q, target=q+1
                const int cbit = 1 << (3 - q), tbit = 1 << (2 - q);
                #pragma unroll
                for (int idx = 0; idx < 16; ++idx) {
                    if ((idx & cbit) && !(idx & tbit)) {
                        const int j = idx | tbit;
                        float tr = ar[idx]; ar[idx] = ar[j]; ar[j] = tr;
                        float ti = ai[idx]; ai[idx] = ai[j]; ai[j] = ti;
                    }
                }
            }
        }

        float qo[4];
        #pragma unroll
        for (int q = 0; q < 4; ++q) {
            const int pb = 1 << (3 - q);
            float s = 0.f;
            #pragma unroll
            for (int idx = 0; idx < 16; ++idx) {
                const float pv = ar[idx]*ar[idx] + ai[idx]*ai[idx];
                s += (idx & pb) ? -pv : pv;
            }
            qo[q] = s;
        }

        float z[10];
        float mx = -1e30f;
        #pragma unroll
        for (int o = 0; o < 10; ++o) {
            float a = fc4b[o];
            #pragma unroll
            for (int j = 0; j < 16; ++j) a = fmaf(feat[j], fc4w[o*20 + j], a);
            #pragma unroll
            for (int j = 0; j < 4;  ++j) a = fmaf(qo[j],  fc4w[o*20 + 16 + j], a);
            z[o] = a; mx = fmaxf(mx, a);
        }
        float se = 0.f;
        #pragma unroll
        for (int o = 0; o < 10; ++o) se += expf(z[o] - mx);
        const float lse = logf(se);
        #pragma unroll
        for (int o = 0; o < 10; ++o) out[(size_t)b*10 + o] = z[o] - mx - lse;
    }
}

// ---------------------------------------------------------------------------
extern "C" void kernel_launch(void* const* d_in, const int* in_sizes, int n_in,
                              void* d_out, int out_size, void* d_ws, size_t ws_size,
                              hipStream_t stream) {
    const float* x     = (const float*)d_in[0];
    const float* c1w   = (const float*)d_in[1];
    const float* c1b   = (const float*)d_in[2];
    const float* c2w   = (const float*)d_in[3];
    const float* c2b   = (const float*)d_in[4];
    const float* fc1w  = (const float*)d_in[5];
    const float* fc1b  = (const float*)d_in[6];
    const float* fc2w  = (const float*)d_in[7];
    const float* fc2b  = (const float*)d_in[8];
    const float* fc3w  = (const float*)d_in[9];
    const float* fc3b  = (const float*)d_in[10];
    const float* qwp   = (const float*)d_in[11];
    const float* fc4w  = (const float*)d_in[12];
    const float* fc4b  = (const float*)d_in[13];
    float* outp = (float*)d_out;

    k_fused<<<1024, 256, 0, stream>>>(x, c1w, c1b, c2w, c2b, fc1w, fc1b,
                                      fc2w, fc2b, fc3w, fc3b, qwp, fc4w, fc4b,
                                      outp);
}